// Round 3
// baseline (585.416 us; speedup 1.0000x reference)
//
#include <hip/hip_runtime.h>
#include <hip/hip_bf16.h>

// Problem constants
#define NB 4
#define NT 256
#define NU 100
#define NH 512      // H_ENC = H_DEC = 512
#define NI 512      // INNER
#define NV 1024     // VOCAB
#define MROWS (NB * NT * NU)   // 102400 joint rows

typedef __attribute__((ext_vector_type(4))) float f32x4;
typedef __attribute__((ext_vector_type(8))) __bf16 bf16x8;

// round-to-nearest-even f32 -> bf16 bits
static __device__ __forceinline__ unsigned int f2bf(float f) {
  unsigned int u = __float_as_uint(f);
  return (u + 0x7FFFu + ((u >> 16) & 1u)) >> 16;
}

// tanh(x) = 1 - 2/(1+e^{2x})
static __device__ __forceinline__ float fast_tanh(float x) {
  float e = __expf(2.f * x);
  return 1.f - 2.f * __builtin_amdgcn_rcpf(1.f + e);
}

// raw workgroup barrier: LDS-visibility only, does NOT drain vmcnt
static __device__ __forceinline__ void lds_barrier() {
  asm volatile("s_waitcnt lgkmcnt(0)\n\ts_barrier" ::: "memory");
}

// ---------------------------------------------------------------------------
// Merged projections: pe[r][i] = enc[r][:] . W1[i][0:512]   (r < 1024)
//                     pd[r][i] = dec[r][:] . W1[i][512:1024] (r < 400)
// fp32, 64x64 tiles, BK=16. Grid (23, 8): x<16 -> enc, else dec.
// ---------------------------------------------------------------------------
__global__ __launch_bounds__(256) void proj_kernel(
    const float* __restrict__ enc, const float* __restrict__ dec,
    const float* __restrict__ W1, float* __restrict__ pe, float* __restrict__ pd) {
  __shared__ float As[64][17];
  __shared__ float Bs[64][17];
  const int bx = blockIdx.x;
  const float* A;
  float* P;
  int Mrows, colOff, row0;
  if (bx < 16) { A = enc; P = pe; Mrows = NB * NT; colOff = 0;  row0 = bx * 64; }
  else         { A = dec; P = pd; Mrows = NB * NU; colOff = NH; row0 = (bx - 16) * 64; }
  const int col0 = blockIdx.y * 64;
  const int tx = threadIdx.x;
  const int tr = tx >> 4, tc = tx & 15;
  const int lr = tx >> 2, lc = (tx & 3) * 4;
  float acc[4][4] = {};
  for (int k0 = 0; k0 < NH; k0 += 16) {
    float4 av = make_float4(0.f, 0.f, 0.f, 0.f);
    if (row0 + lr < Mrows)
      av = *(const float4*)(A + (size_t)(row0 + lr) * NH + k0 + lc);
    float4 bv = *(const float4*)(W1 + (size_t)(col0 + lr) * (NH + NH) + colOff + k0 + lc);
    As[lr][lc] = av.x; As[lr][lc + 1] = av.y; As[lr][lc + 2] = av.z; As[lr][lc + 3] = av.w;
    Bs[lr][lc] = bv.x; Bs[lr][lc + 1] = bv.y; Bs[lr][lc + 2] = bv.z; Bs[lr][lc + 3] = bv.w;
    __syncthreads();
#pragma unroll
    for (int kk = 0; kk < 16; ++kk) {
      float a4[4], b4[4];
#pragma unroll
      for (int i = 0; i < 4; ++i) { a4[i] = As[tr * 4 + i][kk]; b4[i] = Bs[tc * 4 + i][kk]; }
#pragma unroll
      for (int i = 0; i < 4; ++i)
#pragma unroll
        for (int j = 0; j < 4; ++j) acc[i][j] = fmaf(a4[i], b4[j], acc[i][j]);
    }
    __syncthreads();
  }
#pragma unroll
  for (int i = 0; i < 4; ++i) {
    int r = row0 + tr * 4 + i;
    if (r < Mrows) {
#pragma unroll
      for (int j = 0; j < 4; ++j)
        P[(size_t)r * NI + col0 + tc * 4 + j] = acc[i][j];
    }
  }
}

// ---------------------------------------------------------------------------
// W2 f32 -> bf16 bits (1024x512), 4 per thread
// ---------------------------------------------------------------------------
__global__ __launch_bounds__(256) void cvt_w2_kernel(const float* __restrict__ W2,
                                                     unsigned short* __restrict__ w2b) {
  int i = (blockIdx.x * 256 + threadIdx.x) * 4;
  float4 v = *(const float4*)(W2 + i);
  uint2 o;
  o.x = f2bf(v.x) | (f2bf(v.y) << 16);
  o.y = f2bf(v.z) | (f2bf(v.w) << 16);
  *(uint2*)(w2b + i) = o;
}

// ---------------------------------------------------------------------------
// Fused: per block, a 64-row joint panel.
//   Phase 1: hid = tanh(pe+pd+b1) -> bf16 into ldsA (64 x 512, swizzled).
//            A is staged ONCE; never written to HBM.
//   Phase 2: loop 4 vocab-chunks of 256 cols x 16 K-steps (BK=32); W2 chunk
//            (16 KB) reg-prefetched from L2 then ds_written (T14); raw
//            barriers (no vmcnt drain) keep prefetch + out-stores in flight.
// 4 waves; wave tile 64 rows x 64 cols (4x4 16x16x32 frags). LDS 80 KB ->
// 2 blocks/CU for implicit cross-block latency hiding.
// ---------------------------------------------------------------------------
__global__ __launch_bounds__(256, 2) void fused_kernel(
    const float* __restrict__ pe, const float* __restrict__ pd,
    const float* __restrict__ b1, const unsigned short* __restrict__ w2b,
    const float* __restrict__ b2, float* __restrict__ out) {
  __shared__ unsigned char ldsA[64 * 1024];   // 64 rows x 512 k bf16, swizzled
  __shared__ unsigned char ldsB[256 * 64];    // 256 cols x 32 k bf16, swizzled
  const int tx = threadIdx.x;
  const int R0 = blockIdx.x * 64;

  // prefetch B chunk (nt=0, ks=0) into regs, pre-swizzled source order
  uint4 pre[4];
#pragma unroll
  for (int q = 0; q < 4; ++q) {
    int c = q * 256 + tx;              // 16B granule 0..1023
    int cl = c >> 2;                   // local col 0..255
    int sl = (c & 3) ^ ((cl >> 1) & 3);
    pre[q] = *(const uint4*)(w2b + (size_t)cl * NI + sl * 8);
  }

  // Phase 1: hidden tile -> ldsA
#pragma unroll 2
  for (int pass = 0; pass < 16; ++pass) {
    int idx = pass * 256 + tx;         // 4096 granules of 8 elems
    int row = idx >> 6;                // 0..63
    int i0 = (idx & 63) * 8;
    int g = R0 + row;
    int b = g / (NT * NU);
    int rem = g - b * (NT * NU);
    int t = rem / NU;
    int u = rem - t * NU;
    const float* peP = pe + (size_t)(b * NT + t) * NI + i0;
    const float* pdP = pd + (size_t)(b * NU + u) * NI + i0;
    float4 p0 = *(const float4*)peP, p1 = *(const float4*)(peP + 4);
    float4 q0 = *(const float4*)pdP, q1 = *(const float4*)(pdP + 4);
    float4 c0 = *(const float4*)(b1 + i0), c1 = *(const float4*)(b1 + i0 + 4);
    uint4 pk;
    pk.x = f2bf(fast_tanh(p0.x + q0.x + c0.x)) | (f2bf(fast_tanh(p0.y + q0.y + c0.y)) << 16);
    pk.y = f2bf(fast_tanh(p0.z + q0.z + c0.z)) | (f2bf(fast_tanh(p0.w + q0.w + c0.w)) << 16);
    pk.z = f2bf(fast_tanh(p1.x + q1.x + c1.x)) | (f2bf(fast_tanh(p1.y + q1.y + c1.y)) << 16);
    pk.w = f2bf(fast_tanh(p1.z + q1.z + c1.z)) | (f2bf(fast_tanh(p1.w + q1.w + c1.w)) << 16);
    int bo = row * 1024 + ((((i0 >> 3)) ^ (row & 7)) << 4);
    *(uint4*)(ldsA + bo) = pk;
  }

  const int lane = tx & 63, w = tx >> 6;
  const int lr = lane & 15, lq = lane >> 4;

  for (int nt = 0; nt < 4; ++nt) {
    f32x4 acc[4][4];
#pragma unroll
    for (int mf = 0; mf < 4; ++mf)
#pragma unroll
      for (int nf = 0; nf < 4; ++nf)
#pragma unroll
        for (int z = 0; z < 4; ++z) acc[mf][nf][z] = 0.f;

    for (int ks = 0; ks < 16; ++ks) {
      lds_barrier();                   // A: all waves done reading prev B
#pragma unroll
      for (int q = 0; q < 4; ++q)      // linear ds_write (conflict-free)
        *(uint4*)(ldsB + (q * 256 + tx) * 16) = pre[q];
      lds_barrier();                   // B: writes visible, no vmcnt drain

      // issue next chunk's prefetch (latency hides under MFMA below)
      int s = nt * 16 + ks + 1;
      if (s < 64) {
        int nnt = s >> 4, nks = s & 15;
#pragma unroll
        for (int q = 0; q < 4; ++q) {
          int c = q * 256 + tx;
          int cl = c >> 2;
          int sl = (c & 3) ^ ((cl >> 1) & 3);
          pre[q] = *(const uint4*)(w2b + (size_t)(nnt * 256 + cl) * NI + nks * 32 + sl * 8);
        }
      }

      bf16x8 af[4], bfv[4];
#pragma unroll
      for (int mf = 0; mf < 4; ++mf) {
        int row = mf * 16 + lr;
        int slot = ks * 4 + lq;        // k/8 within full 512-k row
        af[mf] = *(const bf16x8*)(ldsA + row * 1024 + ((slot ^ (row & 7)) << 4));
      }
#pragma unroll
      for (int nf = 0; nf < 4; ++nf) {
        int cl = w * 64 + nf * 16 + lr;
        bfv[nf] = *(const bf16x8*)(ldsB + cl * 64 + ((lq ^ ((cl >> 1) & 3)) << 4));
      }
      __builtin_amdgcn_s_setprio(1);
#pragma unroll
      for (int mf = 0; mf < 4; ++mf)
#pragma unroll
        for (int nf = 0; nf < 4; ++nf)
          acc[mf][nf] = __builtin_amdgcn_mfma_f32_16x16x32_bf16(
              af[mf], bfv[nf], acc[mf][nf], 0, 0, 0);
      __builtin_amdgcn_s_setprio(0);
    }

    // epilogue for this 256-col chunk: + b2, fp32 stores (fire-and-forget)
#pragma unroll
    for (int nf = 0; nf < 4; ++nf) {
      int col = nt * 256 + w * 64 + nf * 16 + lr;
      float bb = b2[col];
#pragma unroll
      for (int mf = 0; mf < 4; ++mf) {
#pragma unroll
        for (int j = 0; j < 4; ++j) {
          int grow = R0 + mf * 16 + lq * 4 + j;
          out[(size_t)grow * NV + col] = acc[mf][nf][j] + bb;
        }
      }
    }
  }
}

extern "C" void kernel_launch(void* const* d_in, const int* in_sizes, int n_in,
                              void* d_out, int out_size, void* d_ws, size_t ws_size,
                              hipStream_t stream) {
  const float* enc = (const float*)d_in[0];
  const float* dec = (const float*)d_in[1];
  const float* W1  = (const float*)d_in[2];
  const float* b1  = (const float*)d_in[3];
  const float* W2  = (const float*)d_in[4];
  const float* b2  = (const float*)d_in[5];
  float* out = (float*)d_out;
  char* ws = (char*)d_ws;

  float* pe = (float*)ws;                                   // 2 MB
  float* pd = (float*)(ws + (2u << 20));                    // 0.8 MB
  unsigned short* w2b = (unsigned short*)(ws + (3u << 20)); // 1 MB

  proj_kernel<<<dim3(23, 8), 256, 0, stream>>>(enc, dec, W1, pe, pd);
  cvt_w2_kernel<<<512, 256, 0, stream>>>(W2, w2b);
  fused_kernel<<<MROWS / 64, 256, 0, stream>>>(pe, pd, b1, w2b, b2, out);
}

// Round 4
// 272.439 us; speedup vs baseline: 2.1488x; 2.1488x over previous
//
#include <hip/hip_runtime.h>
#include <hip/hip_bf16.h>

// Problem constants
#define NB 4
#define NT 256
#define NU 100
#define NH 512      // H_ENC = H_DEC = 512
#define NI 512      // INNER
#define NV 1024     // VOCAB
#define MROWS (NB * NT * NU)   // 102400 joint rows

typedef __attribute__((ext_vector_type(4))) float f32x4;
typedef __attribute__((ext_vector_type(8))) __bf16 bf16x8;

// round-to-nearest-even f32 -> bf16 bits
static __device__ __forceinline__ unsigned int f2bf(float f) {
  unsigned int u = __float_as_uint(f);
  return (u + 0x7FFFu + ((u >> 16) & 1u)) >> 16;
}

// tanh(x) = 1 - 2/(1+e^{2x})
static __device__ __forceinline__ float fast_tanh(float x) {
  float e = __expf(2.f * x);
  return 1.f - 2.f * __builtin_amdgcn_rcpf(1.f + e);
}

// async global->LDS, 16B per lane
static __device__ __forceinline__ void gload16(const void* g, void* l) {
  __builtin_amdgcn_global_load_lds(
      (const __attribute__((address_space(1))) unsigned int*)(g),
      (__attribute__((address_space(3))) unsigned int*)(l), 16, 0, 0);
}

// ---------------------------------------------------------------------------
// Merged projections: pe[r][i] = enc[r][:] . W1[i][0:512]   (r < 1024)
//                     pd[r][i] = dec[r][:] . W1[i][512:1024] (r < 400)
// ---------------------------------------------------------------------------
__global__ __launch_bounds__(256) void proj_kernel(
    const float* __restrict__ enc, const float* __restrict__ dec,
    const float* __restrict__ W1, float* __restrict__ pe, float* __restrict__ pd) {
  __shared__ float As[64][17];
  __shared__ float Bs[64][17];
  const int bx = blockIdx.x;
  const float* A;
  float* P;
  int Mrows, colOff, row0;
  if (bx < 16) { A = enc; P = pe; Mrows = NB * NT; colOff = 0;  row0 = bx * 64; }
  else         { A = dec; P = pd; Mrows = NB * NU; colOff = NH; row0 = (bx - 16) * 64; }
  const int col0 = blockIdx.y * 64;
  const int tx = threadIdx.x;
  const int tr = tx >> 4, tc = tx & 15;
  const int lr = tx >> 2, lc = (tx & 3) * 4;
  float acc[4][4] = {};
  for (int k0 = 0; k0 < NH; k0 += 16) {
    float4 av = make_float4(0.f, 0.f, 0.f, 0.f);
    if (row0 + lr < Mrows)
      av = *(const float4*)(A + (size_t)(row0 + lr) * NH + k0 + lc);
    float4 bv = *(const float4*)(W1 + (size_t)(col0 + lr) * (NH + NH) + colOff + k0 + lc);
    As[lr][lc] = av.x; As[lr][lc + 1] = av.y; As[lr][lc + 2] = av.z; As[lr][lc + 3] = av.w;
    Bs[lr][lc] = bv.x; Bs[lr][lc + 1] = bv.y; Bs[lr][lc + 2] = bv.z; Bs[lr][lc + 3] = bv.w;
    __syncthreads();
#pragma unroll
    for (int kk = 0; kk < 16; ++kk) {
      float a4[4], b4[4];
#pragma unroll
      for (int i = 0; i < 4; ++i) { a4[i] = As[tr * 4 + i][kk]; b4[i] = Bs[tc * 4 + i][kk]; }
#pragma unroll
      for (int i = 0; i < 4; ++i)
#pragma unroll
        for (int j = 0; j < 4; ++j) acc[i][j] = fmaf(a4[i], b4[j], acc[i][j]);
    }
    __syncthreads();
  }
#pragma unroll
  for (int i = 0; i < 4; ++i) {
    int r = row0 + tr * 4 + i;
    if (r < Mrows) {
#pragma unroll
      for (int j = 0; j < 4; ++j)
        P[(size_t)r * NI + col0 + tc * 4 + j] = acc[i][j];
    }
  }
}

// ---------------------------------------------------------------------------
// W2 f32 -> bf16 bits (1024x512), 4 per thread
// ---------------------------------------------------------------------------
__global__ __launch_bounds__(256) void cvt_w2_kernel(const float* __restrict__ W2,
                                                     unsigned short* __restrict__ w2b) {
  int i = (blockIdx.x * 256 + threadIdx.x) * 4;
  float4 v = *(const float4*)(W2 + i);
  uint2 o;
  o.x = f2bf(v.x) | (f2bf(v.y) << 16);
  o.y = f2bf(v.z) | (f2bf(v.w) << 16);
  *(uint2*)(w2b + i) = o;
}

// ---------------------------------------------------------------------------
// hid[row][i] = bf16(tanh(pe[b,t,i] + pd[b,u,i] + b1[i])), 8 elements/thread
// ---------------------------------------------------------------------------
__global__ __launch_bounds__(256) void hidden_kernel(
    const float* __restrict__ pe, const float* __restrict__ pd,
    const float* __restrict__ b1, unsigned short* __restrict__ hid) {
  int idx = blockIdx.x * 256 + threadIdx.x;
  int row = idx >> 6;
  int i0 = (idx & 63) * 8;
  int b = row / (NT * NU);
  int rem = row - b * (NT * NU);
  int t = rem / NU;
  int u = rem - t * NU;
  const float* peP = pe + (size_t)(b * NT + t) * NI + i0;
  const float* pdP = pd + (size_t)(b * NU + u) * NI + i0;
  float4 p0 = *(const float4*)peP, p1 = *(const float4*)(peP + 4);
  float4 q0 = *(const float4*)pdP, q1 = *(const float4*)(pdP + 4);
  float4 c0 = *(const float4*)(b1 + i0), c1 = *(const float4*)(b1 + i0 + 4);
  uint4 pk;
  pk.x = f2bf(fast_tanh(p0.x + q0.x + c0.x)) | (f2bf(fast_tanh(p0.y + q0.y + c0.y)) << 16);
  pk.y = f2bf(fast_tanh(p0.z + q0.z + c0.z)) | (f2bf(fast_tanh(p0.w + q0.w + c0.w)) << 16);
  pk.z = f2bf(fast_tanh(p1.x + q1.x + c1.x)) | (f2bf(fast_tanh(p1.y + q1.y + c1.y)) << 16);
  pk.w = f2bf(fast_tanh(p1.z + q1.z + c1.z)) | (f2bf(fast_tanh(p1.w + q1.w + c1.w)) << 16);
  *(uint4*)(hid + (size_t)row * NI + i0) = pk;
}

// ---------------------------------------------------------------------------
// out[r][v] = hid[r][:] . W2[v][:] + b2[v]
// 256x256 tile, BK=64, 512 threads / 8 waves (2Mx4N), wave tile 128x64.
// Double-buffered LDS (128 KB), global_load_lds width-16, both-sides XOR
// swizzle (slot ^= row&7). 2-phase pipeline: STAGE(kt+1) issued BEFORE the
// 64 MFMAs of kt, so the vmcnt(0) inside the single end-of-tile
// __syncthreads() is covered by compute.
// XCD-chunked swizzle: 1600 blocks -> 200/XCD; nt = s/400 pins one vocab
// panel per XCD pair; co-temporal m-sweeps make A L3-resident.
// ---------------------------------------------------------------------------
__global__ __launch_bounds__(512, 2) void gemm_kernel(
    const unsigned short* __restrict__ A,   // hid bf16 [MROWS][512]
    const unsigned short* __restrict__ Bm,  // w2b bf16 [1024][512]
    const float* __restrict__ b2, float* __restrict__ out) {
  __shared__ unsigned char lds[131072];     // [2 buf][A 32KB | B 32KB]
  const int tx = threadIdx.x;
  // XCD-aware remap
  int s = (blockIdx.x & 7) * 200 + (blockIdx.x >> 3);
  const int nt = s / 400;
  const int mt = s - nt * 400;
  const int R0 = mt * 256, C0 = nt * 256;

  const int lane = tx & 63, wid = tx >> 6;
  const int wr = wid >> 2, wc = wid & 3;    // 2x4 wave grid; wave tile 128x64
  const int lr = lane & 15, lq = lane >> 4;

  f32x4 acc[8][4];
#pragma unroll
  for (int mf = 0; mf < 8; ++mf)
#pragma unroll
    for (int nf = 0; nf < 4; ++nf)
#pragma unroll
      for (int z = 0; z < 4; ++z) acc[mf][nf][z] = 0.f;

#define STAGE(KT, BUF) do {                                                   \
    const int k0_ = (KT) * 64;                                                \
    unsigned char* dA_ = lds + (BUF) * 65536;                                 \
    unsigned char* dB_ = dA_ + 32768;                                         \
    _Pragma("unroll")                                                         \
    for (int q = 0; q < 4; ++q) {                                             \
      int c = q * 512 + tx;                                                   \
      int row = c >> 3;                                                       \
      int sl = (c & 7) ^ (row & 7);                                           \
      gload16(A  + (size_t)(R0 + row) * NI + k0_ + sl * 8, dA_ + c * 16);     \
      gload16(Bm + (size_t)(C0 + row) * NI + k0_ + sl * 8, dB_ + c * 16);     \
    }                                                                         \
  } while (0)

  STAGE(0, 0);
  __syncthreads();

  for (int kt = 0; kt < 8; ++kt) {
    const int cur = kt & 1;
    if (kt < 7) STAGE(kt + 1, cur ^ 1);     // in flight during MFMA below
    const unsigned char* bufA = lds + cur * 65536;
    const unsigned char* bufB = bufA + 32768;
#pragma unroll
    for (int kh = 0; kh < 2; ++kh) {
      const int ss = kh * 4 + lq;           // logical 16B k-slot 0..7
      bf16x8 af[8], bfv[4];
#pragma unroll
      for (int nf = 0; nf < 4; ++nf) {
        int col = wc * 64 + nf * 16 + lr;
        bfv[nf] = *(const bf16x8*)(bufB + col * 128 + ((ss ^ (col & 7)) << 4));
      }
#pragma unroll
      for (int mf = 0; mf < 8; ++mf) {
        int row = wr * 128 + mf * 16 + lr;
        af[mf] = *(const bf16x8*)(bufA + row * 128 + ((ss ^ (row & 7)) << 4));
      }
      __builtin_amdgcn_s_setprio(1);
#pragma unroll
      for (int mf = 0; mf < 8; ++mf)
#pragma unroll
        for (int nf = 0; nf < 4; ++nf)
          acc[mf][nf] = __builtin_amdgcn_mfma_f32_16x16x32_bf16(
              af[mf], bfv[nf], acc[mf][nf], 0, 0, 0);
      __builtin_amdgcn_s_setprio(0);
    }
    if (kt < 7) __syncthreads();            // vmcnt(0) covered by compute
  }
#undef STAGE

  // epilogue: + b2, fp32 stores (fire-and-forget; 64B segments per 16 lanes)
#pragma unroll
  for (int nf = 0; nf < 4; ++nf) {
    int col = C0 + wc * 64 + nf * 16 + lr;
    float bb = b2[col];
#pragma unroll
    for (int mf = 0; mf < 8; ++mf) {
#pragma unroll
      for (int j = 0; j < 4; ++j) {
        int grow = R0 + wr * 128 + mf * 16 + lq * 4 + j;
        out[(size_t)grow * NV + col] = acc[mf][nf][j] + bb;
      }
    }
  }
}

// ---------------------------------------------------------------------------
// Fallback fused kernel (round-3, correct but slow; only if ws too small)
// ---------------------------------------------------------------------------
__global__ __launch_bounds__(256, 2) void fused_kernel(
    const float* __restrict__ pe, const float* __restrict__ pd,
    const float* __restrict__ b1, const unsigned short* __restrict__ w2b,
    const float* __restrict__ b2, float* __restrict__ out) {
  __shared__ unsigned char ldsA[64 * 1024];
  __shared__ unsigned char ldsB[256 * 64];
  const int tx = threadIdx.x;
  const int R0 = blockIdx.x * 64;
  uint4 pre[4];
#pragma unroll
  for (int q = 0; q < 4; ++q) {
    int c = q * 256 + tx;
    int cl = c >> 2;
    int sl = (c & 3) ^ ((cl >> 1) & 3);
    pre[q] = *(const uint4*)(w2b + (size_t)cl * NI + sl * 8);
  }
#pragma unroll 2
  for (int pass = 0; pass < 16; ++pass) {
    int idx = pass * 256 + tx;
    int row = idx >> 6;
    int i0 = (idx & 63) * 8;
    int g = R0 + row;
    int b = g / (NT * NU);
    int rem = g - b * (NT * NU);
    int t = rem / NU;
    int u = rem - t * NU;
    const float* peP = pe + (size_t)(b * NT + t) * NI + i0;
    const float* pdP = pd + (size_t)(b * NU + u) * NI + i0;
    float4 p0 = *(const float4*)peP, p1 = *(const float4*)(peP + 4);
    float4 q0 = *(const float4*)pdP, q1 = *(const float4*)(pdP + 4);
    float4 c0 = *(const float4*)(b1 + i0), c1 = *(const float4*)(b1 + i0 + 4);
    uint4 pk;
    pk.x = f2bf(fast_tanh(p0.x + q0.x + c0.x)) | (f2bf(fast_tanh(p0.y + q0.y + c0.y)) << 16);
    pk.y = f2bf(fast_tanh(p0.z + q0.z + c0.z)) | (f2bf(fast_tanh(p0.w + q0.w + c0.w)) << 16);
    pk.z = f2bf(fast_tanh(p1.x + q1.x + c1.x)) | (f2bf(fast_tanh(p1.y + q1.y + c1.y)) << 16);
    pk.w = f2bf(fast_tanh(p1.z + q1.z + c1.z)) | (f2bf(fast_tanh(p1.w + q1.w + c1.w)) << 16);
    int bo = row * 1024 + ((((i0 >> 3)) ^ (row & 7)) << 4);
    *(uint4*)(ldsA + bo) = pk;
  }
  const int lane = tx & 63, w = tx >> 6;
  const int lr = lane & 15, lq = lane >> 4;
  for (int nt = 0; nt < 4; ++nt) {
    f32x4 acc[4][4];
#pragma unroll
    for (int mf = 0; mf < 4; ++mf)
#pragma unroll
      for (int nf = 0; nf < 4; ++nf)
#pragma unroll
        for (int z = 0; z < 4; ++z) acc[mf][nf][z] = 0.f;
    for (int ks = 0; ks < 16; ++ks) {
      __syncthreads();
#pragma unroll
      for (int q = 0; q < 4; ++q)
        *(uint4*)(ldsB + (q * 256 + tx) * 16) = pre[q];
      __syncthreads();
      int sидx = nt * 16 + ks + 1;
      if (sидx < 64) {
        int nnt = sидx >> 4, nks = sидx & 15;
#pragma unroll
        for (int q = 0; q < 4; ++q) {
          int c = q * 256 + tx;
          int cl = c >> 2;
          int sl = (c & 3) ^ ((cl >> 1) & 3);
          pre[q] = *(const uint4*)(w2b + (size_t)(nnt * 256 + cl) * NI + nks * 32 + sl * 8);
        }
      }
      bf16x8 af[4], bfv[4];
#pragma unroll
      for (int mf = 0; mf < 4; ++mf) {
        int row = mf * 16 + lr;
        int slot = ks * 4 + lq;
        af[mf] = *(const bf16x8*)(ldsA + row * 1024 + ((slot ^ (row & 7)) << 4));
      }
#pragma unroll
      for (int nf = 0; nf < 4; ++nf) {
        int cl = w * 64 + nf * 16 + lr;
        bfv[nf] = *(const bf16x8*)(ldsB + cl * 64 + ((lq ^ ((cl >> 1) & 3)) << 4));
      }
#pragma unroll
      for (int mf = 0; mf < 4; ++mf)
#pragma unroll
        for (int nf = 0; nf < 4; ++nf)
          acc[mf][nf] = __builtin_amdgcn_mfma_f32_16x16x32_bf16(
              af[mf], bfv[nf], acc[mf][nf], 0, 0, 0);
    }
#pragma unroll
    for (int nf = 0; nf < 4; ++nf) {
      int col = nt * 256 + w * 64 + nf * 16 + lr;
      float bb = b2[col];
#pragma unroll
      for (int mf = 0; mf < 4; ++mf) {
#pragma unroll
        for (int j = 0; j < 4; ++j) {
          int grow = R0 + mf * 16 + lq * 4 + j;
          out[(size_t)grow * NV + col] = acc[mf][nf][j] + bb;
        }
      }
    }
  }
}

extern "C" void kernel_launch(void* const* d_in, const int* in_sizes, int n_in,
                              void* d_out, int out_size, void* d_ws, size_t ws_size,
                              hipStream_t stream) {
  const float* enc = (const float*)d_in[0];
  const float* dec = (const float*)d_in[1];
  const float* W1  = (const float*)d_in[2];
  const float* b1  = (const float*)d_in[3];
  const float* W2  = (const float*)d_in[4];
  const float* b2  = (const float*)d_in[5];
  float* out = (float*)d_out;
  char* ws = (char*)d_ws;

  float* pe = (float*)ws;                                   // 2 MB
  float* pd = (float*)(ws + (2u << 20));                    // 0.8 MB
  unsigned short* w2b = (unsigned short*)(ws + (3u << 20)); // 1 MB
  unsigned short* hid = (unsigned short*)(ws + (4u << 20)); // 100 MB

  const size_t NEED = (4u << 20) + (size_t)MROWS * NI * 2;

  proj_kernel<<<dim3(23, 8), 256, 0, stream>>>(enc, dec, W1, pe, pd);
  cvt_w2_kernel<<<512, 256, 0, stream>>>(W2, w2b);

  if (ws_size >= NEED) {
    hidden_kernel<<<MROWS * 64 / 256, 256, 0, stream>>>(pe, pd, b1, hid);
    gemm_kernel<<<(MROWS / 256) * (NV / 256), 512, 0, stream>>>(hid, w2b, b2, out);
  } else {
    fused_kernel<<<MROWS / 64, 256, 0, stream>>>(pe, pd, b1, w2b, b2, out);
  }
}